// Round 3
// baseline (550.965 us; speedup 1.0000x reference)
//
#include <hip/hip_runtime.h>
#include <hip/hip_bf16.h>
#include <stdint.h>

#define IN_FEAT 256
#define HIDDEN 128
#define OUT_FEAT 64
#define SCAN_B 1024

// ---------------------------------------------------------------------------
// K0: W_comb[256][64] = W_gc[256][128] @ W_fc[128][64]
//     b_comb[64]      = b_gc @ W_fc + b_fc
// ---------------------------------------------------------------------------
__global__ __launch_bounds__(256) void k_combine_w(
    const float* __restrict__ Wgc, const float* __restrict__ bgc,
    const float* __restrict__ Wfc, const float* __restrict__ bfc,
    float* __restrict__ Wc, float* __restrict__ bc) {
  int idx = blockIdx.x * 256 + threadIdx.x;
  if (idx < IN_FEAT * OUT_FEAT) {
    int r = idx >> 6, c = idx & 63;
    float s = 0.f;
#pragma unroll 8
    for (int j = 0; j < HIDDEN; ++j)
      s = fmaf(Wgc[r * HIDDEN + j], Wfc[j * OUT_FEAT + c], s);
    Wc[idx] = s;
  } else if (idx < IN_FEAT * OUT_FEAT + OUT_FEAT) {
    int c = idx - IN_FEAT * OUT_FEAT;
    float s = bfc[c];
    for (int j = 0; j < HIDDEN; ++j)
      s = fmaf(bgc[j], Wfc[j * OUT_FEAT + c], s);
    bc[c] = s;
  }
}

// ---------------------------------------------------------------------------
// GEMM: h2[N][64] = x[N][256] @ Wc[256][64].  W fully staged in 64KB LDS.
// One row per thread; 64 f32 accumulators; x read via float4.
// ---------------------------------------------------------------------------
__global__ __launch_bounds__(256) void k_gemm(
    const float* __restrict__ x, const float* __restrict__ Wc,
    float* __restrict__ h2, int n) {
  __shared__ float Ws[IN_FEAT * OUT_FEAT];  // 65536 B
  const float4* W4 = (const float4*)Wc;
  float4* Ws4 = (float4*)Ws;
  for (int i = threadIdx.x; i < IN_FEAT * OUT_FEAT / 4; i += 256) Ws4[i] = W4[i];
  __syncthreads();
  int row = blockIdx.x * 256 + threadIdx.x;
  if (row >= n) return;
  float acc[OUT_FEAT];
#pragma unroll
  for (int c = 0; c < OUT_FEAT; ++c) acc[c] = 0.f;
  const float* xr = x + (size_t)row * IN_FEAT;
  for (int k0 = 0; k0 < IN_FEAT; k0 += 4) {
    float4 xv = *(const float4*)(xr + k0);
#pragma unroll
    for (int kk = 0; kk < 4; ++kk) {
      float xs = (&xv.x)[kk];
      const float* wrow = &Ws[(k0 + kk) * OUT_FEAT];
#pragma unroll
      for (int c = 0; c < OUT_FEAT; ++c) acc[c] = fmaf(xs, wrow[c], acc[c]);
    }
  }
  float* o = h2 + (size_t)row * OUT_FEAT;
#pragma unroll
  for (int c = 0; c < OUT_FEAT; c += 4)
    *(float4*)(o + c) = make_float4(acc[c], acc[c + 1], acc[c + 2], acc[c + 3]);
}

// ---------------------------------------------------------------------------
// Count incoming edges per dst (edge_index int32: [2][NE], row0=src, row1=dst)
// ---------------------------------------------------------------------------
__global__ __launch_bounds__(256) void k_count(
    const int* __restrict__ ei, int ne, int* __restrict__ cnt) {
  int stride = gridDim.x * blockDim.x;
  for (int e = blockIdx.x * blockDim.x + threadIdx.x; e < ne; e += stride) {
    int dst = ei[ne + e];
    atomicAdd(&cnt[dst], 1);
  }
}

// dinv[i] = rsqrt(cnt[i] + 1)   (self-loop included)
__global__ __launch_bounds__(256) void k_dinv(
    const int* __restrict__ cnt, float* __restrict__ dinv, int n) {
  int i = blockIdx.x * 256 + threadIdx.x;
  if (i < n) dinv[i] = rsqrtf((float)(cnt[i] + 1));
}

// ---------------------------------------------------------------------------
// 3-kernel exclusive scan of cnt -> row_start (and cursor copy)
// ---------------------------------------------------------------------------
__global__ __launch_bounds__(SCAN_B) void k_scan1(
    const int* __restrict__ cnt, int* __restrict__ incl, int* __restrict__ bsum, int n) {
  __shared__ int sh[SCAN_B];
  int gid = blockIdx.x * SCAN_B + threadIdx.x;
  int v = (gid < n) ? cnt[gid] : 0;
  sh[threadIdx.x] = v;
  __syncthreads();
  for (int d = 1; d < SCAN_B; d <<= 1) {
    int t = (threadIdx.x >= d) ? sh[threadIdx.x - d] : 0;
    __syncthreads();
    sh[threadIdx.x] += t;
    __syncthreads();
  }
  if (gid < n) incl[gid] = sh[threadIdx.x];
  if (threadIdx.x == SCAN_B - 1) bsum[blockIdx.x] = sh[threadIdx.x];
}

__global__ __launch_bounds__(SCAN_B) void k_scan2(
    const int* __restrict__ bsum, int* __restrict__ boff, int nb) {
  __shared__ int sh[SCAN_B];
  int v = (threadIdx.x < nb) ? bsum[threadIdx.x] : 0;
  sh[threadIdx.x] = v;
  __syncthreads();
  for (int d = 1; d < SCAN_B; d <<= 1) {
    int t = (threadIdx.x >= d) ? sh[threadIdx.x - d] : 0;
    __syncthreads();
    sh[threadIdx.x] += t;
    __syncthreads();
  }
  if (threadIdx.x < nb) boff[threadIdx.x] = sh[threadIdx.x] - v;  // exclusive
}

__global__ __launch_bounds__(SCAN_B) void k_scan3(
    const int* __restrict__ cnt, const int* __restrict__ incl,
    const int* __restrict__ boff, int* __restrict__ rs, int* __restrict__ cur, int n) {
  int gid = blockIdx.x * SCAN_B + threadIdx.x;
  if (gid < n) {
    int inc = incl[gid] + boff[gid / SCAN_B];
    int r = inc - cnt[gid];
    rs[gid] = r;
    cur[gid] = r;
    if (gid == n - 1) rs[n] = inc;
  }
}

// ---------------------------------------------------------------------------
// Fill CSR (by dst) with src indices
// ---------------------------------------------------------------------------
__global__ __launch_bounds__(256) void k_fill(
    const int* __restrict__ ei, int ne,
    int* __restrict__ cur, int* __restrict__ csr) {
  int stride = gridDim.x * blockDim.x;
  for (int e = blockIdx.x * blockDim.x + threadIdx.x; e < ne; e += stride) {
    int src = ei[e];
    int dst = ei[ne + e];
    int p = atomicAdd(&cur[dst], 1);
    csr[p] = src;
  }
}

// ---------------------------------------------------------------------------
// Pull-aggregate: one 64-lane wave per node, lane = output feature.
// out[i][c] = dinv_i^2 * h2[i][c] + sum_{s in nbrs(i)} dinv_i*dinv[s]*h2[s][c] + bc[c]
// ---------------------------------------------------------------------------
__global__ __launch_bounds__(256) void k_aggregate(
    const float* __restrict__ h2, const float* __restrict__ dinv,
    const float* __restrict__ bc, const int* __restrict__ rs,
    const int* __restrict__ csr, float* __restrict__ out, int n) {
  int lane = threadIdx.x & 63;
  int wid = blockIdx.x * (blockDim.x >> 6) + (threadIdx.x >> 6);
  int nwaves = gridDim.x * (blockDim.x >> 6);
  float bcv = bc[lane];
  for (int i = wid; i < n; i += nwaves) {
    float di = dinv[i];
    float acc = di * di * h2[(size_t)i * OUT_FEAT + lane] + bcv;
    int j0 = rs[i], j1 = rs[i + 1];
#pragma unroll 2
    for (int j = j0; j < j1; ++j) {
      int s = csr[j];
      acc += di * dinv[s] * h2[(size_t)s * OUT_FEAT + lane];
    }
    out[(size_t)i * OUT_FEAT + lane] = acc;
  }
}

// ---------------------------------------------------------------------------
extern "C" void kernel_launch(void* const* d_in, const int* in_sizes, int n_in,
                              void* d_out, int out_size, void* d_ws, size_t ws_size,
                              hipStream_t stream) {
  const float* x = (const float*)d_in[0];
  const int* ei = (const int*)d_in[1];   // int32 per harness contract
  const float* Wgc = (const float*)d_in[2];
  const float* bgc = (const float*)d_in[3];
  const float* Wfc = (const float*)d_in[4];
  const float* bfc = (const float*)d_in[5];
  float* out = (float*)d_out;

  int N = in_sizes[0] / IN_FEAT;
  int NE = in_sizes[1] / 2;

  // workspace layout (all 4B elements; h2 aligned to 16B). Total ~35 MB.
  float* Wc = (float*)d_ws;
  float* bc = Wc + IN_FEAT * OUT_FEAT;
  float* dinv = bc + OUT_FEAT;
  int* cnt = (int*)(dinv + N);
  int* incl = cnt + N;
  int* bsum = incl + N;
  int* boff = bsum + SCAN_B;
  int* rs = boff + SCAN_B;
  int* cur = rs + ((N + 4) & ~3);
  int* csr = cur + N;
  float* h2 = (float*)((((uintptr_t)(csr + NE)) + 15) & ~(uintptr_t)15);

  hipMemsetAsync(cnt, 0, (size_t)N * sizeof(int), stream);

  k_combine_w<<<(IN_FEAT * OUT_FEAT + OUT_FEAT + 255) / 256, 256, 0, stream>>>(
      Wgc, bgc, Wfc, bfc, Wc, bc);
  k_gemm<<<(N + 255) / 256, 256, 0, stream>>>(x, Wc, h2, N);
  k_count<<<1024, 256, 0, stream>>>(ei, NE, cnt);
  k_dinv<<<(N + 255) / 256, 256, 0, stream>>>(cnt, dinv, N);

  int nsb = (N + SCAN_B - 1) / SCAN_B;
  k_scan1<<<nsb, SCAN_B, 0, stream>>>(cnt, incl, bsum, N);
  k_scan2<<<1, SCAN_B, 0, stream>>>(bsum, boff, nsb);
  k_scan3<<<nsb, SCAN_B, 0, stream>>>(cnt, incl, boff, rs, cur, N);

  k_fill<<<1024, 256, 0, stream>>>(ei, NE, cur, csr);
  k_aggregate<<<2048, 256, 0, stream>>>(h2, dinv, bc, rs, csr, out, N);
}

// Round 4
// 454.712 us; speedup vs baseline: 1.2117x; 1.2117x over previous
//
#include <hip/hip_runtime.h>
#include <hip/hip_bf16.h>
#include <stdint.h>

#define IN_FEAT 256
#define HIDDEN 128
#define OUT_FEAT 64
#define SCAN_B 1024

// ---------------------------------------------------------------------------
// K0: W_comb[256][64] = W_gc[256][128] @ W_fc[128][64]
//     b_comb[64]      = b_gc @ W_fc + b_fc
// ---------------------------------------------------------------------------
__global__ __launch_bounds__(256) void k_combine_w(
    const float* __restrict__ Wgc, const float* __restrict__ bgc,
    const float* __restrict__ Wfc, const float* __restrict__ bfc,
    float* __restrict__ Wc, float* __restrict__ bc) {
  int idx = blockIdx.x * 256 + threadIdx.x;
  if (idx < IN_FEAT * OUT_FEAT) {
    int r = idx >> 6, c = idx & 63;
    float s = 0.f;
#pragma unroll 8
    for (int j = 0; j < HIDDEN; ++j)
      s = fmaf(Wgc[r * HIDDEN + j], Wfc[j * OUT_FEAT + c], s);
    Wc[idx] = s;
  } else if (idx < IN_FEAT * OUT_FEAT + OUT_FEAT) {
    int c = idx - IN_FEAT * OUT_FEAT;
    float s = bfc[c];
    for (int j = 0; j < HIDDEN; ++j)
      s = fmaf(bgc[j], Wfc[j * OUT_FEAT + c], s);
    bc[c] = s;
  }
}

// ---------------------------------------------------------------------------
// GEMM: h2[N][64] = x[N][256] @ Wc[256][64].  W fully staged in 64KB LDS.
// ---------------------------------------------------------------------------
__global__ __launch_bounds__(256) void k_gemm(
    const float* __restrict__ x, const float* __restrict__ Wc,
    float* __restrict__ h2, int n) {
  __shared__ float Ws[IN_FEAT * OUT_FEAT];  // 65536 B
  const float4* W4 = (const float4*)Wc;
  float4* Ws4 = (float4*)Ws;
  for (int i = threadIdx.x; i < IN_FEAT * OUT_FEAT / 4; i += 256) Ws4[i] = W4[i];
  __syncthreads();
  int row = blockIdx.x * 256 + threadIdx.x;
  if (row >= n) return;
  float acc[OUT_FEAT];
#pragma unroll
  for (int c = 0; c < OUT_FEAT; ++c) acc[c] = 0.f;
  const float* xr = x + (size_t)row * IN_FEAT;
  for (int k0 = 0; k0 < IN_FEAT; k0 += 4) {
    float4 xv = *(const float4*)(xr + k0);
#pragma unroll
    for (int kk = 0; kk < 4; ++kk) {
      float xs = (&xv.x)[kk];
      const float* wrow = &Ws[(k0 + kk) * OUT_FEAT];
#pragma unroll
      for (int c = 0; c < OUT_FEAT; ++c) acc[c] = fmaf(xs, wrow[c], acc[c]);
    }
  }
  float* o = h2 + (size_t)row * OUT_FEAT;
#pragma unroll
  for (int c = 0; c < OUT_FEAT; c += 4)
    *(float4*)(o + c) = make_float4(acc[c], acc[c + 1], acc[c + 2], acc[c + 3]);
}

// ---------------------------------------------------------------------------
// Count incoming edges per dst AND record each edge's rank within its dst.
// 1 edge per thread: no dependent atomic chains within a thread.
// ---------------------------------------------------------------------------
__global__ __launch_bounds__(256) void k_count(
    const int* __restrict__ ei, int ne, int* __restrict__ cnt,
    int* __restrict__ rank) {
  int e = blockIdx.x * 256 + threadIdx.x;
  if (e < ne) {
    int dst = ei[ne + e];
    rank[e] = atomicAdd(&cnt[dst], 1);
  }
}

// ---------------------------------------------------------------------------
// 3-kernel exclusive scan of cnt -> row_start; scan3 also computes dinv
// ---------------------------------------------------------------------------
__global__ __launch_bounds__(SCAN_B) void k_scan1(
    const int* __restrict__ cnt, int* __restrict__ incl, int* __restrict__ bsum, int n) {
  __shared__ int sh[SCAN_B];
  int gid = blockIdx.x * SCAN_B + threadIdx.x;
  int v = (gid < n) ? cnt[gid] : 0;
  sh[threadIdx.x] = v;
  __syncthreads();
  for (int d = 1; d < SCAN_B; d <<= 1) {
    int t = (threadIdx.x >= d) ? sh[threadIdx.x - d] : 0;
    __syncthreads();
    sh[threadIdx.x] += t;
    __syncthreads();
  }
  if (gid < n) incl[gid] = sh[threadIdx.x];
  if (threadIdx.x == SCAN_B - 1) bsum[blockIdx.x] = sh[threadIdx.x];
}

__global__ __launch_bounds__(SCAN_B) void k_scan2(
    const int* __restrict__ bsum, int* __restrict__ boff, int nb) {
  __shared__ int sh[SCAN_B];
  int v = (threadIdx.x < nb) ? bsum[threadIdx.x] : 0;
  sh[threadIdx.x] = v;
  __syncthreads();
  for (int d = 1; d < SCAN_B; d <<= 1) {
    int t = (threadIdx.x >= d) ? sh[threadIdx.x - d] : 0;
    __syncthreads();
    sh[threadIdx.x] += t;
    __syncthreads();
  }
  if (threadIdx.x < nb) boff[threadIdx.x] = sh[threadIdx.x] - v;  // exclusive
}

__global__ __launch_bounds__(SCAN_B) void k_scan3(
    const int* __restrict__ cnt, const int* __restrict__ incl,
    const int* __restrict__ boff, int* __restrict__ rs,
    float* __restrict__ dinv, int n) {
  int gid = blockIdx.x * SCAN_B + threadIdx.x;
  if (gid < n) {
    int c = cnt[gid];
    int inc = incl[gid] + boff[gid / SCAN_B];
    rs[gid] = inc - c;
    dinv[gid] = rsqrtf((float)(c + 1));  // self-loop included
    if (gid == n - 1) rs[n] = inc;
  }
}

// ---------------------------------------------------------------------------
// Fill CSR (by dst) with src indices — atomic-free scatter
// ---------------------------------------------------------------------------
__global__ __launch_bounds__(256) void k_fill(
    const int* __restrict__ ei, int ne, const int* __restrict__ rs,
    const int* __restrict__ rank, int* __restrict__ csr) {
  int e = blockIdx.x * 256 + threadIdx.x;
  if (e < ne) {
    int src = ei[e];
    int dst = ei[ne + e];
    csr[rs[dst] + rank[e]] = src;
  }
}

// ---------------------------------------------------------------------------
// Pull-aggregate: one wave per node, 4 neighbors in flight.
// Lane l: sub = l>>4 (neighbor slot), fl = l&15 (float4 feature group).
// out[i] = dinv_i^2*h2[i] + sum_s dinv_i*dinv_s*h2[s] + bc
// ---------------------------------------------------------------------------
__global__ __launch_bounds__(256) void k_aggregate(
    const float* __restrict__ h2, const float* __restrict__ dinv,
    const float* __restrict__ bc, const int* __restrict__ rs,
    const int* __restrict__ csr, float* __restrict__ out, int n) {
  int lane = threadIdx.x & 63;
  int sub = lane >> 4;
  int fl = lane & 15;
  int wid = blockIdx.x * (blockDim.x >> 6) + (threadIdx.x >> 6);
  int nwaves = gridDim.x * (blockDim.x >> 6);
  float4 bcv = *(const float4*)(bc + fl * 4);
  for (int i = wid; i < n; i += nwaves) {
    float di = dinv[i];
    int j0 = rs[i], j1 = rs[i + 1];
    float4 acc = make_float4(0.f, 0.f, 0.f, 0.f);
#pragma unroll 2
    for (int j = j0 + sub; j < j1; j += 4) {
      int s = csr[j];
      float w = di * dinv[s];
      float4 hv = *(const float4*)(h2 + (size_t)s * OUT_FEAT + fl * 4);
      acc.x = fmaf(w, hv.x, acc.x);
      acc.y = fmaf(w, hv.y, acc.y);
      acc.z = fmaf(w, hv.z, acc.z);
      acc.w = fmaf(w, hv.w, acc.w);
    }
    // reduce across the 4 sub-groups (lanes l, l^16, l^32, l^48 share fl)
#pragma unroll
    for (int m = 16; m <= 32; m <<= 1) {
      acc.x += __shfl_xor(acc.x, m, 64);
      acc.y += __shfl_xor(acc.y, m, 64);
      acc.z += __shfl_xor(acc.z, m, 64);
      acc.w += __shfl_xor(acc.w, m, 64);
    }
    if (sub == 0) {
      float4 hv = *(const float4*)(h2 + (size_t)i * OUT_FEAT + fl * 4);
      float w = di * di;
      float4 r;
      r.x = fmaf(w, hv.x, acc.x + bcv.x);
      r.y = fmaf(w, hv.y, acc.y + bcv.y);
      r.z = fmaf(w, hv.z, acc.z + bcv.z);
      r.w = fmaf(w, hv.w, acc.w + bcv.w);
      *(float4*)(out + (size_t)i * OUT_FEAT + fl * 4) = r;
    }
  }
}

// ---------------------------------------------------------------------------
extern "C" void kernel_launch(void* const* d_in, const int* in_sizes, int n_in,
                              void* d_out, int out_size, void* d_ws, size_t ws_size,
                              hipStream_t stream) {
  const float* x = (const float*)d_in[0];
  const int* ei = (const int*)d_in[1];   // int32 per harness contract
  const float* Wgc = (const float*)d_in[2];
  const float* bgc = (const float*)d_in[3];
  const float* Wfc = (const float*)d_in[4];
  const float* bfc = (const float*)d_in[5];
  float* out = (float*)d_out;

  int N = in_sizes[0] / IN_FEAT;
  int NE = in_sizes[1] / 2;

  // workspace layout (all 4B elements; h2 aligned to 16B). Total ~42 MB.
  float* Wc = (float*)d_ws;
  float* bc = Wc + IN_FEAT * OUT_FEAT;
  float* dinv = bc + OUT_FEAT;
  int* cnt = (int*)(dinv + N);
  int* incl = cnt + N;
  int* bsum = incl + N;
  int* boff = bsum + SCAN_B;
  int* rs = boff + SCAN_B;
  int* rank = rs + ((N + 4) & ~3);
  int* csr = rank + NE;
  float* h2 = (float*)((((uintptr_t)(csr + NE)) + 15) & ~(uintptr_t)15);

  hipMemsetAsync(cnt, 0, (size_t)N * sizeof(int), stream);

  k_combine_w<<<(IN_FEAT * OUT_FEAT + OUT_FEAT + 255) / 256, 256, 0, stream>>>(
      Wgc, bgc, Wfc, bfc, Wc, bc);
  k_gemm<<<(N + 255) / 256, 256, 0, stream>>>(x, Wc, h2, N);
  k_count<<<(NE + 255) / 256, 256, 0, stream>>>(ei, NE, cnt, rank);

  int nsb = (N + SCAN_B - 1) / SCAN_B;
  k_scan1<<<nsb, SCAN_B, 0, stream>>>(cnt, incl, bsum, N);
  k_scan2<<<1, SCAN_B, 0, stream>>>(bsum, boff, nsb);
  k_scan3<<<nsb, SCAN_B, 0, stream>>>(cnt, incl, boff, rs, dinv, N);

  k_fill<<<(NE + 255) / 256, 256, 0, stream>>>(ei, NE, rs, rank, csr);
  k_aggregate<<<4096, 256, 0, stream>>>(h2, dinv, bc, rs, csr, out, N);
}